// Round 1
// 585.656 us; speedup vs baseline: 1.0450x; 1.0450x over previous
//
#include <hip/hip_runtime.h>
#include <stdint.h>

typedef unsigned short u16;
typedef __attribute__((ext_vector_type(8))) __bf16 bf16x8;
typedef __attribute__((ext_vector_type(4))) float f32x4;
typedef __attribute__((ext_vector_type(4))) u16 u16x4;
typedef __attribute__((ext_vector_type(8))) u16 u16x8;

#define BM 128
#define BN 128
#define BK 32
#define MTOT 4096

__device__ __forceinline__ u16 f2bf(float f) {
  union { float f; uint32_t u; } x; x.f = f;
  uint32_t r = x.u + 0x7FFFu + ((x.u >> 16) & 1u);
  return (u16)(r >> 16);
}
__device__ __forceinline__ float bf2f(u16 h) {
  union { uint32_t u; float f; } x; x.u = ((uint32_t)h) << 16;
  return x.f;
}

__device__ __forceinline__ void gload16(const void* g, void* lds) {
  __builtin_amdgcn_global_load_lds(
      (const __attribute__((address_space(1))) void*)g,
      (__attribute__((address_space(3))) void*)lds, 16, 0, 0);
}

struct ViewParams {
  const void* A;    // [M][lda] row-major; fp32 if AF32 else bf16
  const u16* BT;    // [N][ldab] row-major bf16 (B transposed)
  void* C;          // bf16 unless CF32
  const float* bias;
  int ldab, lda, N;
  int kspan;            // K elements per k-chunk (loop length)
  size_t partStride;    // element stride between k-chunk output buffers
};
struct Params5 { ViewParams v[5]; };

// FLAGS: 1 = transposed bf16 store (C is [N][4096]), 2 = +bias, 4 = relu
template <int FLAGS, bool AF32, bool CF32>
__global__ __launch_bounds__(256) void gemm_kernel(Params5 p, int tilesPerView,
                                                   int ntiles, int kchunks) {
  constexpr int ABYTES = AF32 ? (BM * BK * 4) : (BM * BK * 2);
  __shared__ __align__(16) char smem[ABYTES + BN * BK * 2];
  u16* Bs = (u16*)(smem + ABYTES);

  const int bid = blockIdx.x;
  const int view = bid / tilesPerView;
  const int t = bid - view * tilesPerView;
  const int kc = t % kchunks;
  const int t2 = t / kchunks;
  const int nt = t2 % ntiles;
  const int mt = t2 / ntiles;
  ViewParams vp = p.v[view];
  const int ldab = vp.ldab, lda = vp.lda, N = vp.N;
  const int m0 = mt * BM, n0 = nt * BN;
  const int kbase = kc * vp.kspan;

  const int tid = threadIdx.x;
  const int wave = tid >> 6;
  const int lane = tid & 63;

  // ---- B staging (bf16): rows of 32 u16 = 64B = 4 chunks, XOR-4 swizzle
  const int srow = lane >> 2;
  const int slot4 = lane & 3;
  const int rB0 = wave * 32 + srow;
  const int rB1 = rB0 + 16;
  const int cB0 = slot4 ^ ((rB0 >> 1) & 3);
  const int cB1 = slot4 ^ ((rB1 >> 1) & 3);
  const u16* gB0 = vp.BT + (size_t)(n0 + rB0) * ldab + kbase + cB0 * 8;
  const u16* gB1 = vp.BT + (size_t)(n0 + rB1) * ldab + kbase + cB1 * 8;
  u16* lB0 = Bs + (wave * 32) * 32;
  u16* lB1 = Bs + (wave * 32 + 16) * 32;

  // ---- A staging
  const float* gAf[4];
  float* lAf[4];
  const u16 *gAb0 = nullptr, *gAb1 = nullptr;
  u16 *lAb0 = nullptr, *lAb1 = nullptr;
  if constexpr (AF32) {
    const float* Af = (const float*)vp.A;
    const int arow = lane >> 3;
    const int slot8 = lane & 7;
#pragma unroll
    for (int i = 0; i < 4; i++) {
      int r = wave * 32 + i * 8 + arow;
      int c = slot8 ^ (r & 7);
      gAf[i] = Af + (size_t)(m0 + r) * lda + kbase + c * 4;
      lAf[i] = (float*)smem + (wave * 32 + i * 8) * 32;
    }
  } else {
    const u16* Ab = (const u16*)vp.A;
    const int rA0 = wave * 32 + srow;
    const int rA1 = rA0 + 16;
    const int cA0 = slot4 ^ ((rA0 >> 1) & 3);
    const int cA1 = slot4 ^ ((rA1 >> 1) & 3);
    gAb0 = Ab + (size_t)(m0 + rA0) * lda + kbase + cA0 * 8;
    gAb1 = Ab + (size_t)(m0 + rA1) * lda + kbase + cA1 * 8;
    lAb0 = (u16*)smem + (wave * 32) * 32;
    lAb1 = (u16*)smem + (wave * 32 + 16) * 32;
  }

  // ---- fragment offsets (swizzle-aware); wave covers a 64x64 quadrant
  const int lm = lane & 15;
  const int q = lane >> 4;
  const int wm = (wave >> 1) * 64;
  const int wn = (wave & 1) * 64;
  int aoff0[4], aoff1[4], boff[4];
#pragma unroll
  for (int i = 0; i < 4; i++) {
    int ml = wm + i * 16 + lm;
    if constexpr (AF32) {
      aoff0[i] = ml * 32 + ((2 * q) ^ (ml & 7)) * 4;
      aoff1[i] = ml * 32 + ((2 * q + 1) ^ (ml & 7)) * 4;
    } else {
      aoff0[i] = ml * 32 + (q ^ ((ml >> 1) & 3)) * 8;
    }
    int nl = wn + i * 16 + lm;
    boff[i] = nl * 32 + (q ^ ((nl >> 1) & 3)) * 8;
  }

  f32x4 acc[4][4];
#pragma unroll
  for (int i = 0; i < 4; i++)
#pragma unroll
    for (int j = 0; j < 4; j++) acc[i][j] = 0.0f;

  for (int ks = 0; ks < vp.kspan; ks += BK) {
    if constexpr (AF32) {
#pragma unroll
      for (int i = 0; i < 4; i++) { gload16(gAf[i], lAf[i]); gAf[i] += BK; }
    } else {
      gload16(gAb0, lAb0); gload16(gAb1, lAb1);
      gAb0 += BK; gAb1 += BK;
    }
    gload16(gB0, lB0); gload16(gB1, lB1);
    gB0 += BK; gB1 += BK;
    __syncthreads();

    bf16x8 af[4], bfr[4];
#pragma unroll
    for (int i = 0; i < 4; i++) {
      if constexpr (AF32) {
        f32x4 lo = *(const f32x4*)((const float*)smem + aoff0[i]);
        f32x4 hi = *(const f32x4*)((const float*)smem + aoff1[i]);
        bf16x8 a;
#pragma unroll
        for (int tt = 0; tt < 4; tt++) { a[tt] = (__bf16)lo[tt]; a[tt + 4] = (__bf16)hi[tt]; }
        af[i] = a;
      } else {
        af[i] = *(const bf16x8*)((const u16*)smem + aoff0[i]);
      }
    }
#pragma unroll
    for (int j = 0; j < 4; j++) bfr[j] = *(const bf16x8*)(Bs + boff[j]);
#pragma unroll
    for (int i = 0; i < 4; i++)
#pragma unroll
      for (int j = 0; j < 4; j++)
        acc[i][j] = __builtin_amdgcn_mfma_f32_16x16x32_bf16(af[i], bfr[j], acc[i][j], 0, 0, 0);
    __syncthreads();
  }

  // ---- epilogue. C/D layout: col = lane&15, row = quad*4 + reg.
#pragma unroll
  for (int j = 0; j < 4; j++) {
    const int n = n0 + wn + j * 16 + lm;
    float bv = 0.0f;
    if (FLAGS & 2) bv = vp.bias[n];
#pragma unroll
    for (int i = 0; i < 4; i++) {
      const int mb = m0 + wm + i * 16 + q * 4;
      float v0 = acc[i][j][0], v1 = acc[i][j][1], v2 = acc[i][j][2], v3 = acc[i][j][3];
      if (FLAGS & 2) { v0 += bv; v1 += bv; v2 += bv; v3 += bv; }
      if (FLAGS & 4) {
        v0 = fmaxf(v0, 0.0f); v1 = fmaxf(v1, 0.0f);
        v2 = fmaxf(v2, 0.0f); v3 = fmaxf(v3, 0.0f);
      }
      if constexpr ((FLAGS & 1) != 0) {
        u16x4 pk;
        pk[0] = f2bf(v0); pk[1] = f2bf(v1); pk[2] = f2bf(v2); pk[3] = f2bf(v3);
        *(u16x4*)((u16*)vp.C + (size_t)kc * vp.partStride + (size_t)n * MTOT + mb) = pk;
      } else if constexpr (CF32) {
        float* cp = (float*)vp.C + (size_t)kc * vp.partStride + (size_t)mb * N + n;
        cp[0] = v0; cp[N] = v1; cp[2 * N] = v2; cp[3 * N] = v3;
      } else {
        u16* cp = (u16*)vp.C + (size_t)kc * vp.partStride + (size_t)mb * N + n;
        cp[0] = f2bf(v0); cp[N] = f2bf(v1); cp[2 * N] = f2bf(v2); cp[3 * N] = f2bf(v3);
      }
    }
  }
}

// merged fp32 -> bf16 adj conversion, all 5 views.
// One f32x4 per lane (16B read) -> u16x4 (8B write): both streams fully
// coalesced (old version read 32B/lane via two stride-32 f32x4 loads ->
// 2x transactions per load instr).
struct CvtParams { const float* src[5]; u16* dst; };
__global__ __launch_bounds__(256) void cvt_kernel(CvtParams cp) {
  long i = (long)blockIdx.x * 256 + threadIdx.x;   // 5 * 2^22 threads exactly
  int v = (int)(i >> 22);
  long r = i & ((1L << 22) - 1);
  f32x4 a = ((const f32x4*)cp.src[v])[r];
  u16x4 o;
#pragma unroll
  for (int t = 0; t < 4; t++) o[t] = f2bf(a[t]);
  ((u16x4*)cp.dst)[i] = o;
}

// combine k-chunk bf16 partials of H (row-major [4096][256] per view):
// H = relu(sum_kc parts + b1), bias indexed by COLUMN (e & 255).
struct CombParams { const u16* parts; u16* out; const float* b[5]; int kchunks; };
__global__ __launch_bounds__(256) void comb_h_kernel(CombParams cp) {
  int idx = blockIdx.x * 256 + threadIdx.x;   // 5 * 2^17 threads exactly
  int v = idx >> 17;
  int e = (idx & 131071) << 3;
  float acc[8] = {0, 0, 0, 0, 0, 0, 0, 0};
  for (int kc = 0; kc < cp.kchunks; kc++) {
    u16x8 t = *(const u16x8*)(cp.parts + (((size_t)(kc * 5 + v)) << 20) + e);
#pragma unroll
    for (int j = 0; j < 8; j++) acc[j] += bf2f(t[j]);
  }
  const float* bp = cp.b[v] + (e & 255);
  u16x8 o;
#pragma unroll
  for (int j = 0; j < 8; j++) o[j] = f2bf(fmaxf(acc[j] + bp[j], 0.0f));
  *(u16x8*)(cp.out + (((size_t)v) << 20) + e) = o;
}

// combine fp32 final partials: out = sum_kc parts + b2 (row-major [4096][128])
struct CombFParams { const float* parts; float* out; const float* b[5]; int kchunks; };
__global__ __launch_bounds__(256) void combf_kernel(CombFParams cp) {
  int idx = blockIdx.x * 256 + threadIdx.x;   // 5 * 2^16 threads exactly
  int v = idx >> 16;
  int e = (idx & 65535) << 3;
  float acc[8] = {0, 0, 0, 0, 0, 0, 0, 0};
  for (int kc = 0; kc < cp.kchunks; kc++) {
    const float* pp = cp.parts + (((size_t)(kc * 5 + v)) << 19) + e;
    f32x4 a = *(const f32x4*)pp;
    f32x4 b = *(const f32x4*)(pp + 4);
#pragma unroll
    for (int j = 0; j < 4; j++) { acc[j] += a[j]; acc[j + 4] += b[j]; }
  }
  const float* bp = cp.b[v] + (e & 127);
  f32x4 o0, o1;
#pragma unroll
  for (int j = 0; j < 4; j++) { o0[j] = acc[j] + bp[j]; o1[j] = acc[j + 4] + bp[j + 4]; }
  float* op = cp.out + (((size_t)v) << 19) + e;
  *(f32x4*)op = o0;
  *(f32x4*)(op + 4) = o1;
}

struct PrepParams {
  const float* W1[5]; u16* W1T[5];
  const float* W2[5]; u16* W2T[5];
  const float* xl; float* xlp;
  int d[5]; int Kp[5];
};

__global__ void prep_kernel(PrepParams p, int total) {
  int idx = blockIdx.x * 256 + threadIdx.x;
  if (idx >= total) return;
  int off = 0;
#pragma unroll
  for (int v = 0; v < 5; v++) {
    int sz = 256 * p.Kp[v];
    if (idx < off + sz) {
      int r = idx - off;
      int n = r / p.Kp[v];
      int k = r - n * p.Kp[v];
      p.W1T[v][r] = (k < p.d[v]) ? f2bf(p.W1[v][(size_t)k * 256 + n]) : (u16)0;
      return;
    }
    off += sz;
  }
#pragma unroll
  for (int v = 0; v < 5; v++) {
    if (idx < off + 128 * 256) {
      int r = idx - off;
      int n = r >> 8, k = r & 255;
      p.W2T[v][r] = f2bf(p.W2[v][(size_t)k * 128 + n]);
      return;
    }
    off += 128 * 256;
  }
  {
    int r = idx - off;
    int m = r / 96, k = r - m * 96;
    p.xlp[r] = (k < 93) ? p.xl[(size_t)m * 93 + k] : 0.0f;
  }
}

extern "C" void kernel_launch(void* const* d_in, const int* in_sizes, int n_in,
                              void* d_out, int out_size, void* d_ws, size_t ws_size,
                              hipStream_t stream) {
  (void)in_sizes; (void)n_in; (void)out_size;
  static const int dims[5] = {768, 64, 93, 256, 768};
  static const int Kp[5]   = {768, 64, 96, 256, 768};

  const float *adjf[5], *xf[5], *W1f[5], *b1f[5], *W2f[5], *b2f[5];
  for (int v = 0; v < 5; v++) {
    adjf[v] = (const float*)d_in[6 * v + 0];
    xf[v]   = (const float*)d_in[6 * v + 1];
    W1f[v]  = (const float*)d_in[6 * v + 2];
    b1f[v]  = (const float*)d_in[6 * v + 3];
    W2f[v]  = (const float*)d_in[6 * v + 4];
    b2f[v]  = (const float*)d_in[6 * v + 5];
  }

  const size_t VIEW = (size_t)256 * 4096;   // 1,048,576 elements
  const size_t TV   = (size_t)128 * 4096;   // 524,288 elements (T^T per view)
  char* ws = (char*)d_ws;
  size_t off = 0;
  auto carve = [&](size_t bytes) { char* pp = ws + off; off += (bytes + 15) & ~(size_t)15; return pp; };
  u16* W1T[5]; for (int v = 0; v < 5; v++) W1T[v] = (u16*)carve((size_t)256 * Kp[v] * 2);
  u16* W2T[5]; for (int v = 0; v < 5; v++) W2T[v] = (u16*)carve((size_t)128 * 256 * 2);
  float* xlp = (float*)carve((size_t)4096 * 96 * 4);
  u16* Y1T = (u16*)carve(5 * VIEW * 2);      // later reused as TT (T^T, 5MB of 10MB)
  u16* PARTS = (u16*)carve(2 * 5 * VIEW * 2); // bf16 H partials; reused as fp32 final partials
  u16* HT = (u16*)carve(5 * VIEW * 2);       // H row-major [4096][256] per view
  u16* adjb = (u16*)carve((size_t)5 * 4096 * 4096 * 2);
  const bool ksplit = ws_size >= off;
  u16* TT = Y1T;            // alias: Y1T dead before TT is written
  float* PARTSF = (float*)PARTS;

  // prep: weight transposes (fp32 -> bf16) + fp32 liwc padding
  PrepParams pp;
  int prepTot = 0;
  for (int v = 0; v < 5; v++) {
    pp.W1[v] = W1f[v]; pp.W1T[v] = W1T[v];
    pp.W2[v] = W2f[v]; pp.W2T[v] = W2T[v];
    pp.d[v] = dims[v]; pp.Kp[v] = Kp[v];
    prepTot += 256 * Kp[v];
  }
  pp.xl = xf[2]; pp.xlp = xlp;
  prepTot += 5 * 128 * 256 + 4096 * 96;
  prep_kernel<<<(prepTot + 255) / 256, 256, 0, stream>>>(pp, prepTot);

  // Phase A: Y1T = (x @ W1)^T   (A fp32, transposed bf16 store)
  Params5 pa;
  for (int v = 0; v < 5; v++)
    pa.v[v] = ViewParams{ (v == 2 ? (const void*)xlp : (const void*)xf[v]), W1T[v], Y1T + v * VIEW,
                          nullptr, Kp[v], Kp[v], 256, Kp[v], 0 };
  gemm_kernel<1, true, false><<<320, 256, 0, stream>>>(pa, 64, 2, 1);

  // adj fp32 -> bf16 (single merged launch; adjb lands L3-warm for phase B)
  CvtParams cv;
  for (int v = 0; v < 5; v++) cv.src[v] = adjf[v];
  cv.dst = adjb;
  cvt_kernel<<<81920, 256, 0, stream>>>(cv);

  if (ksplit) {
    // Phase B: PARTS[kc][v] = adj @ Y1 partials, ROW-MAJOR [4096][256], K split in 2
    Params5 pb;
    for (int v = 0; v < 5; v++)
      pb.v[v] = ViewParams{ adjb + (size_t)v * 4096 * 4096, Y1T + v * VIEW, PARTS + v * VIEW,
                            nullptr, 4096, 4096, 256, 2048, 5 * VIEW };
    gemm_kernel<0, false, false><<<640, 256, 0, stream>>>(pb, 128, 2, 2);

    // combine1: H = relu(sum parts + b1)  (row-major, column bias)
    CombParams c1{ PARTS, HT, { b1f[0], b1f[1], b1f[2], b1f[3], b1f[4] }, 2 };
    comb_h_kernel<<<2560, 256, 0, stream>>>(c1);

    // Phase C': TT = (H @ W2)^T  — tiny GEMM, matches reference associativity
    Params5 pc;
    for (int v = 0; v < 5; v++)
      pc.v[v] = ViewParams{ HT + v * VIEW, W2T[v], TT + v * TV,
                            nullptr, 256, 256, 128, 256, 0 };
    gemm_kernel<1, false, false><<<160, 256, 0, stream>>>(pc, 32, 1, 1);

    // Phase D': PARTSF[kc][v] = adj @ T partials (fp32, row-major [4096][128]), K split in 2
    Params5 pd;
    for (int v = 0; v < 5; v++)
      pd.v[v] = ViewParams{ adjb + (size_t)v * 4096 * 4096, TT + v * TV, PARTSF + v * TV,
                            nullptr, 4096, 4096, 128, 2048, 5 * TV };
    gemm_kernel<0, false, true><<<320, 256, 0, stream>>>(pd, 64, 1, 2);

    // combine2: out = sum parts + b2
    CombFParams c2{ PARTSF, (float*)d_out, { b2f[0], b2f[1], b2f[2], b2f[3], b2f[4] }, 2 };
    combf_kernel<<<1280, 256, 0, stream>>>(c2);
  } else {
    // fallback: no K-split. H row-major direct with bias+relu (FLAGS=6: col bias = n)
    Params5 pb;
    for (int v = 0; v < 5; v++)
      pb.v[v] = ViewParams{ adjb + (size_t)v * 4096 * 4096, Y1T + v * VIEW, HT + v * VIEW,
                            b1f[v], 4096, 4096, 256, 4096, 0 };
    gemm_kernel<6, false, false><<<320, 256, 0, stream>>>(pb, 64, 2, 1);

    Params5 pc;
    for (int v = 0; v < 5; v++)
      pc.v[v] = ViewParams{ HT + v * VIEW, W2T[v], TT + v * TV,
                            nullptr, 256, 256, 128, 256, 0 };
    gemm_kernel<1, false, false><<<160, 256, 0, stream>>>(pc, 32, 1, 1);

    Params5 pd;
    float* outp = (float*)d_out;
    for (int v = 0; v < 5; v++)
      pd.v[v] = ViewParams{ adjb + (size_t)v * 4096 * 4096, TT + v * TV, outp + v * TV,
                            b2f[v], 4096, 4096, 128, 4096, 0 };
    gemm_kernel<2, false, true><<<160, 256, 0, stream>>>(pd, 32, 1, 1);
  }
}

// Round 4
// 579.376 us; speedup vs baseline: 1.0564x; 1.0108x over previous
//
#include <hip/hip_runtime.h>
#include <stdint.h>

typedef unsigned short u16;
typedef __attribute__((ext_vector_type(8))) __bf16 bf16x8;
typedef __attribute__((ext_vector_type(4))) float f32x4;
typedef __attribute__((ext_vector_type(4))) u16 u16x4;
typedef __attribute__((ext_vector_type(8))) u16 u16x8;

#define BM 128
#define BN 128
#define BK 32
#define MTOT 4096

__device__ __forceinline__ u16 f2bf(float f) {
  union { float f; uint32_t u; } x; x.f = f;
  uint32_t r = x.u + 0x7FFFu + ((x.u >> 16) & 1u);
  return (u16)(r >> 16);
}
__device__ __forceinline__ float bf2f(u16 h) {
  union { uint32_t u; float f; } x; x.u = ((uint32_t)h) << 16;
  return x.f;
}

__device__ __forceinline__ void gload16(const void* g, void* lds) {
  __builtin_amdgcn_global_load_lds(
      (const __attribute__((address_space(1))) void*)g,
      (__attribute__((address_space(3))) void*)lds, 16, 0, 0);
}

struct ViewParams {
  const void* A;    // [M][lda] row-major; fp32 if AF32 else bf16
  const u16* BT;    // [N][ldab] row-major bf16 (B transposed)
  void* C;          // bf16 unless CF32
  const float* bias;
  int ldab, lda, N;
  int kspan;            // K elements per k-chunk (loop length)
  size_t partStride;    // element stride between k-chunk output buffers
};
struct Params5 { ViewParams v[5]; };

// FLAGS: 1 = transposed bf16 store (C is [N][4096]), 2 = +bias, 4 = relu
template <int FLAGS, bool AF32, bool CF32>
__global__ __launch_bounds__(256) void gemm_kernel(Params5 p, int tilesPerView,
                                                   int ntiles, int kchunks) {
  constexpr int ABYTES = AF32 ? (BM * BK * 4) : (BM * BK * 2);
  __shared__ __align__(16) char smem[ABYTES + BN * BK * 2];
  u16* Bs = (u16*)(smem + ABYTES);

  const int bid = blockIdx.x;
  const int view = bid / tilesPerView;
  const int t = bid - view * tilesPerView;
  const int kc = t % kchunks;
  const int t2 = t / kchunks;
  const int nt = t2 % ntiles;
  const int mt = t2 / ntiles;
  ViewParams vp = p.v[view];
  const int ldab = vp.ldab, lda = vp.lda, N = vp.N;
  const int m0 = mt * BM, n0 = nt * BN;
  const int kbase = kc * vp.kspan;

  const int tid = threadIdx.x;
  const int wave = tid >> 6;
  const int lane = tid & 63;

  // ---- B staging (bf16): rows of 32 u16 = 64B = 4 chunks, XOR-4 swizzle
  const int srow = lane >> 2;
  const int slot4 = lane & 3;
  const int rB0 = wave * 32 + srow;
  const int rB1 = rB0 + 16;
  const int cB0 = slot4 ^ ((rB0 >> 1) & 3);
  const int cB1 = slot4 ^ ((rB1 >> 1) & 3);
  const u16* gB0 = vp.BT + (size_t)(n0 + rB0) * ldab + kbase + cB0 * 8;
  const u16* gB1 = vp.BT + (size_t)(n0 + rB1) * ldab + kbase + cB1 * 8;
  u16* lB0 = Bs + (wave * 32) * 32;
  u16* lB1 = Bs + (wave * 32 + 16) * 32;

  // ---- A staging
  const float* gAf[4];
  float* lAf[4];
  const u16 *gAb0 = nullptr, *gAb1 = nullptr;
  u16 *lAb0 = nullptr, *lAb1 = nullptr;
  if constexpr (AF32) {
    const float* Af = (const float*)vp.A;
    const int arow = lane >> 3;
    const int slot8 = lane & 7;
#pragma unroll
    for (int i = 0; i < 4; i++) {
      int r = wave * 32 + i * 8 + arow;
      int c = slot8 ^ (r & 7);
      gAf[i] = Af + (size_t)(m0 + r) * lda + kbase + c * 4;
      lAf[i] = (float*)smem + (wave * 32 + i * 8) * 32;
    }
  } else {
    const u16* Ab = (const u16*)vp.A;
    const int rA0 = wave * 32 + srow;
    const int rA1 = rA0 + 16;
    const int cA0 = slot4 ^ ((rA0 >> 1) & 3);
    const int cA1 = slot4 ^ ((rA1 >> 1) & 3);
    gAb0 = Ab + (size_t)(m0 + rA0) * lda + kbase + cA0 * 8;
    gAb1 = Ab + (size_t)(m0 + rA1) * lda + kbase + cA1 * 8;
    lAb0 = (u16*)smem + (wave * 32) * 32;
    lAb1 = (u16*)smem + (wave * 32 + 16) * 32;
  }

  // ---- fragment offsets (swizzle-aware); wave covers a 64x64 quadrant
  const int lm = lane & 15;
  const int q = lane >> 4;
  const int wm = (wave >> 1) * 64;
  const int wn = (wave & 1) * 64;
  int aoff0[4], aoff1[4], boff[4];
#pragma unroll
  for (int i = 0; i < 4; i++) {
    int ml = wm + i * 16 + lm;
    if constexpr (AF32) {
      aoff0[i] = ml * 32 + ((2 * q) ^ (ml & 7)) * 4;
      aoff1[i] = ml * 32 + ((2 * q + 1) ^ (ml & 7)) * 4;
    } else {
      aoff0[i] = ml * 32 + (q ^ ((ml >> 1) & 3)) * 8;
    }
    int nl = wn + i * 16 + lm;
    boff[i] = nl * 32 + (q ^ ((nl >> 1) & 3)) * 8;
  }

  f32x4 acc[4][4];
#pragma unroll
  for (int i = 0; i < 4; i++)
#pragma unroll
    for (int j = 0; j < 4; j++) acc[i][j] = 0.0f;

  for (int ks = 0; ks < vp.kspan; ks += BK) {
    if constexpr (AF32) {
#pragma unroll
      for (int i = 0; i < 4; i++) { gload16(gAf[i], lAf[i]); gAf[i] += BK; }
    } else {
      gload16(gAb0, lAb0); gload16(gAb1, lAb1);
      gAb0 += BK; gAb1 += BK;
    }
    gload16(gB0, lB0); gload16(gB1, lB1);
    gB0 += BK; gB1 += BK;
    __syncthreads();

    bf16x8 af[4], bfr[4];
#pragma unroll
    for (int i = 0; i < 4; i++) {
      if constexpr (AF32) {
        f32x4 lo = *(const f32x4*)((const float*)smem + aoff0[i]);
        f32x4 hi = *(const f32x4*)((const float*)smem + aoff1[i]);
        bf16x8 a;
#pragma unroll
        for (int tt = 0; tt < 4; tt++) { a[tt] = (__bf16)lo[tt]; a[tt + 4] = (__bf16)hi[tt]; }
        af[i] = a;
      } else {
        af[i] = *(const bf16x8*)((const u16*)smem + aoff0[i]);
      }
    }
#pragma unroll
    for (int j = 0; j < 4; j++) bfr[j] = *(const bf16x8*)(Bs + boff[j]);
#pragma unroll
    for (int i = 0; i < 4; i++)
#pragma unroll
      for (int j = 0; j < 4; j++)
        acc[i][j] = __builtin_amdgcn_mfma_f32_16x16x32_bf16(af[i], bfr[j], acc[i][j], 0, 0, 0);
    __syncthreads();
  }

  // ---- epilogue. C/D layout: col = lane&15, row = quad*4 + reg.
#pragma unroll
  for (int j = 0; j < 4; j++) {
    const int n = n0 + wn + j * 16 + lm;
    float bv = 0.0f;
    if (FLAGS & 2) bv = vp.bias[n];
#pragma unroll
    for (int i = 0; i < 4; i++) {
      const int mb = m0 + wm + i * 16 + q * 4;
      float v0 = acc[i][j][0], v1 = acc[i][j][1], v2 = acc[i][j][2], v3 = acc[i][j][3];
      if (FLAGS & 2) { v0 += bv; v1 += bv; v2 += bv; v3 += bv; }
      if (FLAGS & 4) {
        v0 = fmaxf(v0, 0.0f); v1 = fmaxf(v1, 0.0f);
        v2 = fmaxf(v2, 0.0f); v3 = fmaxf(v3, 0.0f);
      }
      if constexpr ((FLAGS & 1) != 0) {
        u16x4 pk;
        pk[0] = f2bf(v0); pk[1] = f2bf(v1); pk[2] = f2bf(v2); pk[3] = f2bf(v3);
        *(u16x4*)((u16*)vp.C + (size_t)kc * vp.partStride + (size_t)n * MTOT + mb) = pk;
      } else if constexpr (CF32) {
        float* cp = (float*)vp.C + (size_t)kc * vp.partStride + (size_t)mb * N + n;
        cp[0] = v0; cp[N] = v1; cp[2 * N] = v2; cp[3 * N] = v3;
      } else {
        u16* cp = (u16*)vp.C + (size_t)kc * vp.partStride + (size_t)mb * N + n;
        cp[0] = f2bf(v0); cp[N] = f2bf(v1); cp[2 * N] = f2bf(v2); cp[3 * N] = f2bf(v3);
      }
    }
  }
}

// combine k-chunk bf16 partials of H (row-major [4096][256] per view):
// H = relu(sum_kc parts + b1), bias indexed by COLUMN (e & 255).
struct CombParams { const u16* parts; u16* out; const float* b[5]; int kchunks; };
__global__ __launch_bounds__(256) void comb_h_kernel(CombParams cp) {
  int idx = blockIdx.x * 256 + threadIdx.x;   // 5 * 2^17 threads exactly
  int v = idx >> 17;
  int e = (idx & 131071) << 3;
  float acc[8] = {0, 0, 0, 0, 0, 0, 0, 0};
  for (int kc = 0; kc < cp.kchunks; kc++) {
    u16x8 t = *(const u16x8*)(cp.parts + (((size_t)(kc * 5 + v)) << 20) + e);
#pragma unroll
    for (int j = 0; j < 8; j++) acc[j] += bf2f(t[j]);
  }
  const float* bp = cp.b[v] + (e & 255);
  u16x8 o;
#pragma unroll
  for (int j = 0; j < 8; j++) o[j] = f2bf(fmaxf(acc[j] + bp[j], 0.0f));
  *(u16x8*)(cp.out + (((size_t)v) << 20) + e) = o;
}

// combine fp32 final partials: out = sum_kc parts + b2 (row-major [4096][128])
struct CombFParams { const float* parts; float* out; const float* b[5]; int kchunks; };
__global__ __launch_bounds__(256) void combf_kernel(CombFParams cp) {
  int idx = blockIdx.x * 256 + threadIdx.x;   // 5 * 2^16 threads exactly
  int v = idx >> 16;
  int e = (idx & 65535) << 3;
  float acc[8] = {0, 0, 0, 0, 0, 0, 0, 0};
  for (int kc = 0; kc < cp.kchunks; kc++) {
    const float* pp = cp.parts + (((size_t)(kc * 5 + v)) << 19) + e;
    f32x4 a = *(const f32x4*)pp;
    f32x4 b = *(const f32x4*)(pp + 4);
#pragma unroll
    for (int j = 0; j < 4; j++) { acc[j] += a[j]; acc[j + 4] += b[j]; }
  }
  const float* bp = cp.b[v] + (e & 127);
  f32x4 o0, o1;
#pragma unroll
  for (int j = 0; j < 4; j++) { o0[j] = acc[j] + bp[j]; o1[j] = acc[j + 4] + bp[j + 4]; }
  float* op = cp.out + (((size_t)v) << 19) + e;
  *(f32x4*)op = o0;
  *(f32x4*)(op + 4) = o1;
}

struct PrepParams {
  const float* W1[5]; u16* W1T[5];
  const float* W2[5]; u16* W2T[5];
  const float* xl; float* xlp;
  int d[5]; int Kp[5];
};

__global__ void prep_kernel(PrepParams p, int total) {
  int idx = blockIdx.x * 256 + threadIdx.x;
  if (idx >= total) return;
  int off = 0;
#pragma unroll
  for (int v = 0; v < 5; v++) {
    int sz = 256 * p.Kp[v];
    if (idx < off + sz) {
      int r = idx - off;
      int n = r / p.Kp[v];
      int k = r - n * p.Kp[v];
      p.W1T[v][r] = (k < p.d[v]) ? f2bf(p.W1[v][(size_t)k * 256 + n]) : (u16)0;
      return;
    }
    off += sz;
  }
#pragma unroll
  for (int v = 0; v < 5; v++) {
    if (idx < off + 128 * 256) {
      int r = idx - off;
      int n = r >> 8, k = r & 255;
      p.W2T[v][r] = f2bf(p.W2[v][(size_t)k * 128 + n]);
      return;
    }
    off += 128 * 256;
  }
  {
    int r = idx - off;
    int m = r / 96, k = r - m * 96;
    p.xlp[r] = (k < 93) ? p.xl[(size_t)m * 93 + k] : 0.0f;
  }
}

extern "C" void kernel_launch(void* const* d_in, const int* in_sizes, int n_in,
                              void* d_out, int out_size, void* d_ws, size_t ws_size,
                              hipStream_t stream) {
  (void)in_sizes; (void)n_in; (void)out_size;
  static const int dims[5] = {768, 64, 93, 256, 768};
  static const int Kp[5]   = {768, 64, 96, 256, 768};

  const float *adjf[5], *xf[5], *W1f[5], *b1f[5], *W2f[5], *b2f[5];
  for (int v = 0; v < 5; v++) {
    adjf[v] = (const float*)d_in[6 * v + 0];
    xf[v]   = (const float*)d_in[6 * v + 1];
    W1f[v]  = (const float*)d_in[6 * v + 2];
    b1f[v]  = (const float*)d_in[6 * v + 3];
    W2f[v]  = (const float*)d_in[6 * v + 4];
    b2f[v]  = (const float*)d_in[6 * v + 5];
  }

  const size_t VIEW = (size_t)256 * 4096;   // 1,048,576 elements
  const size_t TV   = (size_t)128 * 4096;   // 524,288 elements (T^T per view)
  char* ws = (char*)d_ws;
  size_t off = 0;
  auto carve = [&](size_t bytes) { char* pp = ws + off; off += (bytes + 15) & ~(size_t)15; return pp; };
  u16* W1T[5]; for (int v = 0; v < 5; v++) W1T[v] = (u16*)carve((size_t)256 * Kp[v] * 2);
  u16* W2T[5]; for (int v = 0; v < 5; v++) W2T[v] = (u16*)carve((size_t)128 * 256 * 2);
  float* xlp = (float*)carve((size_t)4096 * 96 * 4);
  u16* Y1T = (u16*)carve(5 * VIEW * 2);      // later reused as TT (T^T, 5MB of 10MB)
  u16* PARTS = (u16*)carve(2 * 5 * VIEW * 2); // bf16 H partials; reused as fp32 final partials
  u16* HT = (u16*)carve(5 * VIEW * 2);       // H row-major [4096][256] per view
  const bool ksplit = ws_size >= off;
  u16* TT = Y1T;            // alias: Y1T dead before TT is written
  float* PARTSF = (float*)PARTS;

  // prep: weight transposes (fp32 -> bf16) + fp32 liwc padding
  PrepParams pp;
  int prepTot = 0;
  for (int v = 0; v < 5; v++) {
    pp.W1[v] = W1f[v]; pp.W1T[v] = W1T[v];
    pp.W2[v] = W2f[v]; pp.W2T[v] = W2T[v];
    pp.d[v] = dims[v]; pp.Kp[v] = Kp[v];
    prepTot += 256 * Kp[v];
  }
  pp.xl = xf[2]; pp.xlp = xlp;
  prepTot += 5 * 128 * 256 + 4096 * 96;
  prep_kernel<<<(prepTot + 255) / 256, 256, 0, stream>>>(pp, prepTot);

  // Phase A: Y1T = (x @ W1)^T   (A fp32, transposed bf16 store)
  Params5 pa;
  for (int v = 0; v < 5; v++)
    pa.v[v] = ViewParams{ (v == 2 ? (const void*)xlp : (const void*)xf[v]), W1T[v], Y1T + v * VIEW,
                          nullptr, Kp[v], Kp[v], 256, Kp[v], 0 };
  gemm_kernel<1, true, false><<<320, 256, 0, stream>>>(pa, 64, 2, 1);

  if (ksplit) {
    // Phase B: PARTS[kc][v] = adj @ Y1 partials, ROW-MAJOR [4096][256], K split in 2.
    // A = adj fp32 directly (no cvt pre-pass; in-register RNE f32->bf16 during
    // fragment load — identical numerics to the old cvt path).
    Params5 pb;
    for (int v = 0; v < 5; v++)
      pb.v[v] = ViewParams{ adjf[v], Y1T + v * VIEW, PARTS + v * VIEW,
                            nullptr, 4096, 4096, 256, 2048, 5 * VIEW };
    gemm_kernel<0, true, false><<<640, 256, 0, stream>>>(pb, 128, 2, 2);

    // combine1: H = relu(sum parts + b1)  (row-major, column bias)
    CombParams c1{ PARTS, HT, { b1f[0], b1f[1], b1f[2], b1f[3], b1f[4] }, 2 };
    comb_h_kernel<<<2560, 256, 0, stream>>>(c1);

    // Phase C': TT = (H @ W2)^T  — tiny GEMM, matches reference associativity
    Params5 pc;
    for (int v = 0; v < 5; v++)
      pc.v[v] = ViewParams{ HT + v * VIEW, W2T[v], TT + v * TV,
                            nullptr, 256, 256, 128, 256, 0 };
    gemm_kernel<1, false, false><<<160, 256, 0, stream>>>(pc, 32, 1, 1);

    // Phase D': PARTSF[kc][v] = adj @ T partials (fp32, row-major [4096][128]),
    // K split in 2, A = adj fp32 directly.
    Params5 pd;
    for (int v = 0; v < 5; v++)
      pd.v[v] = ViewParams{ adjf[v], TT + v * TV, PARTSF + v * TV,
                            nullptr, 4096, 4096, 128, 2048, 5 * TV };
    gemm_kernel<0, true, true><<<320, 256, 0, stream>>>(pd, 64, 1, 2);

    // combine2: out = sum parts + b2
    CombFParams c2{ PARTSF, (float*)d_out, { b2f[0], b2f[1], b2f[2], b2f[3], b2f[4] }, 2 };
    combf_kernel<<<1280, 256, 0, stream>>>(c2);
  } else {
    // fallback: no K-split, fp32 adj reads, direct writes
    Params5 pb;
    for (int v = 0; v < 5; v++)
      pb.v[v] = ViewParams{ adjf[v], Y1T + v * VIEW, HT + v * VIEW,
                            b1f[v], 4096, 4096, 256, 4096, 0 };
    gemm_kernel<6, true, false><<<320, 256, 0, stream>>>(pb, 64, 2, 1);

    Params5 pc;
    for (int v = 0; v < 5; v++)
      pc.v[v] = ViewParams{ HT + v * VIEW, W2T[v], TT + v * TV,
                            nullptr, 256, 256, 128, 256, 0 };
    gemm_kernel<1, false, false><<<160, 256, 0, stream>>>(pc, 32, 1, 1);

    Params5 pd;
    float* outp = (float*)d_out;
    for (int v = 0; v < 5; v++)
      pd.v[v] = ViewParams{ adjf[v], TT + v * TV, outp + v * TV,
                            b2f[v], 4096, 4096, 128, 4096, 0 };
    gemm_kernel<2, true, true><<<160, 256, 0, stream>>>(pd, 32, 1, 1);
  }
}

// Round 5
// 574.235 us; speedup vs baseline: 1.0658x; 1.0090x over previous
//
#include <hip/hip_runtime.h>
#include <stdint.h>

typedef unsigned short u16;
typedef __attribute__((ext_vector_type(8))) __bf16 bf16x8;
typedef __attribute__((ext_vector_type(4))) float f32x4;
typedef __attribute__((ext_vector_type(4))) u16 u16x4;
typedef __attribute__((ext_vector_type(8))) u16 u16x8;

#define BM 128
#define BN 128
#define BK 32
#define MTOT 4096

__device__ __forceinline__ u16 f2bf(float f) {
  union { float f; uint32_t u; } x; x.f = f;
  uint32_t r = x.u + 0x7FFFu + ((x.u >> 16) & 1u);
  return (u16)(r >> 16);
}
__device__ __forceinline__ float bf2f(u16 h) {
  union { uint32_t u; float f; } x; x.u = ((uint32_t)h) << 16;
  return x.f;
}

__device__ __forceinline__ void gload16(const void* g, void* lds) {
  __builtin_amdgcn_global_load_lds(
      (const __attribute__((address_space(1))) void*)g,
      (__attribute__((address_space(3))) void*)lds, 16, 0, 0);
}

struct ViewParams {
  const void* A;    // [M][lda] row-major; fp32 if AF32 else bf16
  const u16* BT;    // [N][ldab] row-major bf16 (B transposed)
  void* C;          // bf16 unless CF32
  const float* bias;
  int ldab, lda, N;
  int kspan;            // K elements per k-chunk (loop length)
  size_t partStride;    // element stride between k-chunk output buffers
};
struct Params5 { ViewParams v[5]; };

// FLAGS: 1 = transposed bf16 store (C is [N][4096]), 2 = +bias, 4 = relu
// Main loop is double-buffered (T3 minimum 2-phase): stage(next) is issued
// BEFORE compute(cur), so the global->LDS latency of tile t+1 hides under
// the ds_read+MFMA of tile t. One barrier per K-step (implicit vmcnt(0)
// drain at the barrier guarantees the staged tile has landed).
template <int FLAGS, bool AF32, bool CF32>
__global__ __launch_bounds__(256) void gemm_kernel(Params5 p, int tilesPerView,
                                                   int ntiles, int kchunks) {
  constexpr int ABYTES = AF32 ? (BM * BK * 4) : (BM * BK * 2);
  constexpr int BUFB = ABYTES + BN * BK * 2;
  __shared__ __align__(16) char smem[2 * BUFB];

  const int bid = blockIdx.x;
  const int view = bid / tilesPerView;
  const int t = bid - view * tilesPerView;
  const int kc = t % kchunks;
  const int t2 = t / kchunks;
  const int nt = t2 % ntiles;
  const int mt = t2 / ntiles;
  ViewParams vp = p.v[view];
  const int ldab = vp.ldab, lda = vp.lda, N = vp.N;
  const int m0 = mt * BM, n0 = nt * BN;
  const int kbase = kc * vp.kspan;

  const int tid = threadIdx.x;
  const int wave = tid >> 6;
  const int lane = tid & 63;

  // ---- B staging (bf16): rows of 32 u16 = 64B = 4 chunks, XOR-4 swizzle
  const int srow = lane >> 2;
  const int slot4 = lane & 3;
  const int rB0 = wave * 32 + srow;
  const int rB1 = rB0 + 16;
  const int cB0 = slot4 ^ ((rB0 >> 1) & 3);
  const int cB1 = slot4 ^ ((rB1 >> 1) & 3);
  const u16* gB0 = vp.BT + (size_t)(n0 + rB0) * ldab + kbase + cB0 * 8;
  const u16* gB1 = vp.BT + (size_t)(n0 + rB1) * ldab + kbase + cB1 * 8;
  const int lB0_off = ABYTES + (wave * 32) * 32 * 2;
  const int lB1_off = ABYTES + (wave * 32 + 16) * 32 * 2;

  // ---- A staging
  const float* gAf[4];
  const u16 *gAb0 = nullptr, *gAb1 = nullptr;
  int lA_off[4];
  if constexpr (AF32) {
    const float* Af = (const float*)vp.A;
    const int arow = lane >> 3;
    const int slot8 = lane & 7;
#pragma unroll
    for (int i = 0; i < 4; i++) {
      int r = wave * 32 + i * 8 + arow;
      int c = slot8 ^ (r & 7);
      gAf[i] = Af + (size_t)(m0 + r) * lda + kbase + c * 4;
      lA_off[i] = (wave * 32 + i * 8) * 32 * 4;
    }
  } else {
    const u16* Ab = (const u16*)vp.A;
    const int rA0 = wave * 32 + srow;
    const int rA1 = rA0 + 16;
    const int cA0 = slot4 ^ ((rA0 >> 1) & 3);
    const int cA1 = slot4 ^ ((rA1 >> 1) & 3);
    gAb0 = Ab + (size_t)(m0 + rA0) * lda + kbase + cA0 * 8;
    gAb1 = Ab + (size_t)(m0 + rA1) * lda + kbase + cA1 * 8;
    lA_off[0] = (wave * 32) * 32 * 2;
    lA_off[1] = (wave * 32 + 16) * 32 * 2;
  }

  // ---- fragment offsets (swizzle-aware); wave covers a 64x64 quadrant
  const int lm = lane & 15;
  const int q = lane >> 4;
  const int wm = (wave >> 1) * 64;
  const int wn = (wave & 1) * 64;
  int aoff0[4], aoff1[4], boff[4];
#pragma unroll
  for (int i = 0; i < 4; i++) {
    int ml = wm + i * 16 + lm;
    if constexpr (AF32) {
      aoff0[i] = ml * 32 + ((2 * q) ^ (ml & 7)) * 4;
      aoff1[i] = ml * 32 + ((2 * q + 1) ^ (ml & 7)) * 4;
    } else {
      aoff0[i] = ml * 32 + (q ^ ((ml >> 1) & 3)) * 8;
    }
    int nl = wn + i * 16 + lm;
    boff[i] = nl * 32 + (q ^ ((nl >> 1) & 3)) * 8;
  }

  f32x4 acc[4][4];
#pragma unroll
  for (int i = 0; i < 4; i++)
#pragma unroll
    for (int j = 0; j < 4; j++) acc[i][j] = 0.0f;

  auto stage = [&](char* bufp) {
    if constexpr (AF32) {
#pragma unroll
      for (int i = 0; i < 4; i++) { gload16(gAf[i], bufp + lA_off[i]); gAf[i] += BK; }
    } else {
      gload16(gAb0, bufp + lA_off[0]);
      gload16(gAb1, bufp + lA_off[1]);
      gAb0 += BK; gAb1 += BK;
    }
    gload16(gB0, bufp + lB0_off);
    gload16(gB1, bufp + lB1_off);
    gB0 += BK; gB1 += BK;
  };

  auto compute = [&](const char* bufp) {
    bf16x8 af[4], bfr[4];
#pragma unroll
    for (int i = 0; i < 4; i++) {
      if constexpr (AF32) {
        f32x4 lo = *(const f32x4*)((const float*)bufp + aoff0[i]);
        f32x4 hi = *(const f32x4*)((const float*)bufp + aoff1[i]);
        bf16x8 a;
#pragma unroll
        for (int tt = 0; tt < 4; tt++) { a[tt] = (__bf16)lo[tt]; a[tt + 4] = (__bf16)hi[tt]; }
        af[i] = a;
      } else {
        af[i] = *(const bf16x8*)((const u16*)bufp + aoff0[i]);
      }
    }
    const u16* Bs = (const u16*)(bufp + ABYTES);
#pragma unroll
    for (int j = 0; j < 4; j++) bfr[j] = *(const bf16x8*)(Bs + boff[j]);
#pragma unroll
    for (int i = 0; i < 4; i++)
#pragma unroll
      for (int j = 0; j < 4; j++)
        acc[i][j] = __builtin_amdgcn_mfma_f32_16x16x32_bf16(af[i], bfr[j], acc[i][j], 0, 0, 0);
  };

  char* curp = smem;
  char* nxtp = smem + BUFB;
  stage(curp);
  __syncthreads();                  // vmcnt(0) drained by compiler before barrier
  const int nsteps = vp.kspan / BK;
  for (int s = 0; s < nsteps - 1; s++) {
    stage(nxtp);                    // issue next tile early; latency hides under compute
    compute(curp);
    __syncthreads();                // drains next-tile loads; WAR-protects cur buffer
    char* tmp = curp; curp = nxtp; nxtp = tmp;
  }
  compute(curp);

  // ---- epilogue. C/D layout: col = lane&15, row = quad*4 + reg.
#pragma unroll
  for (int j = 0; j < 4; j++) {
    const int n = n0 + wn + j * 16 + lm;
    float bv = 0.0f;
    if (FLAGS & 2) bv = vp.bias[n];
#pragma unroll
    for (int i = 0; i < 4; i++) {
      const int mb = m0 + wm + i * 16 + q * 4;
      float v0 = acc[i][j][0], v1 = acc[i][j][1], v2 = acc[i][j][2], v3 = acc[i][j][3];
      if (FLAGS & 2) { v0 += bv; v1 += bv; v2 += bv; v3 += bv; }
      if (FLAGS & 4) {
        v0 = fmaxf(v0, 0.0f); v1 = fmaxf(v1, 0.0f);
        v2 = fmaxf(v2, 0.0f); v3 = fmaxf(v3, 0.0f);
      }
      if constexpr ((FLAGS & 1) != 0) {
        u16x4 pk;
        pk[0] = f2bf(v0); pk[1] = f2bf(v1); pk[2] = f2bf(v2); pk[3] = f2bf(v3);
        *(u16x4*)((u16*)vp.C + (size_t)kc * vp.partStride + (size_t)n * MTOT + mb) = pk;
      } else if constexpr (CF32) {
        float* cp = (float*)vp.C + (size_t)kc * vp.partStride + (size_t)mb * N + n;
        cp[0] = v0; cp[N] = v1; cp[2 * N] = v2; cp[3 * N] = v3;
      } else {
        u16* cp = (u16*)vp.C + (size_t)kc * vp.partStride + (size_t)mb * N + n;
        cp[0] = f2bf(v0); cp[N] = f2bf(v1); cp[2 * N] = f2bf(v2); cp[3 * N] = f2bf(v3);
      }
    }
  }
}

// combine k-chunk bf16 partials of H (row-major [4096][256] per view):
// H = relu(sum_kc parts + b1), bias indexed by COLUMN (e & 255).
struct CombParams { const u16* parts; u16* out; const float* b[5]; int kchunks; };
__global__ __launch_bounds__(256) void comb_h_kernel(CombParams cp) {
  int idx = blockIdx.x * 256 + threadIdx.x;   // 5 * 2^17 threads exactly
  int v = idx >> 17;
  int e = (idx & 131071) << 3;
  float acc[8] = {0, 0, 0, 0, 0, 0, 0, 0};
  for (int kc = 0; kc < cp.kchunks; kc++) {
    u16x8 t = *(const u16x8*)(cp.parts + (((size_t)(kc * 5 + v)) << 20) + e);
#pragma unroll
    for (int j = 0; j < 8; j++) acc[j] += bf2f(t[j]);
  }
  const float* bp = cp.b[v] + (e & 255);
  u16x8 o;
#pragma unroll
  for (int j = 0; j < 8; j++) o[j] = f2bf(fmaxf(acc[j] + bp[j], 0.0f));
  *(u16x8*)(cp.out + (((size_t)v) << 20) + e) = o;
}

// combine fp32 final partials: out = sum_kc parts + b2 (row-major [4096][128])
struct CombFParams { const float* parts; float* out; const float* b[5]; int kchunks; };
__global__ __launch_bounds__(256) void combf_kernel(CombFParams cp) {
  int idx = blockIdx.x * 256 + threadIdx.x;   // 5 * 2^16 threads exactly
  int v = idx >> 16;
  int e = (idx & 65535) << 3;
  float acc[8] = {0, 0, 0, 0, 0, 0, 0, 0};
  for (int kc = 0; kc < cp.kchunks; kc++) {
    const float* pp = cp.parts + (((size_t)(kc * 5 + v)) << 19) + e;
    f32x4 a = *(const f32x4*)pp;
    f32x4 b = *(const f32x4*)(pp + 4);
#pragma unroll
    for (int j = 0; j < 4; j++) { acc[j] += a[j]; acc[j + 4] += b[j]; }
  }
  const float* bp = cp.b[v] + (e & 127);
  f32x4 o0, o1;
#pragma unroll
  for (int j = 0; j < 4; j++) { o0[j] = acc[j] + bp[j]; o1[j] = acc[j + 4] + bp[j + 4]; }
  float* op = cp.out + (((size_t)v) << 19) + e;
  *(f32x4*)op = o0;
  *(f32x4*)(op + 4) = o1;
}

struct PrepParams {
  const float* W1[5]; u16* W1T[5];
  const float* W2[5]; u16* W2T[5];
  const float* xl; float* xlp;
  int d[5]; int Kp[5];
};

__global__ void prep_kernel(PrepParams p, int total) {
  int idx = blockIdx.x * 256 + threadIdx.x;
  if (idx >= total) return;
  int off = 0;
#pragma unroll
  for (int v = 0; v < 5; v++) {
    int sz = 256 * p.Kp[v];
    if (idx < off + sz) {
      int r = idx - off;
      int n = r / p.Kp[v];
      int k = r - n * p.Kp[v];
      p.W1T[v][r] = (k < p.d[v]) ? f2bf(p.W1[v][(size_t)k * 256 + n]) : (u16)0;
      return;
    }
    off += sz;
  }
#pragma unroll
  for (int v = 0; v < 5; v++) {
    if (idx < off + 128 * 256) {
      int r = idx - off;
      int n = r >> 8, k = r & 255;
      p.W2T[v][r] = f2bf(p.W2[v][(size_t)k * 128 + n]);
      return;
    }
    off += 128 * 256;
  }
  {
    int r = idx - off;
    int m = r / 96, k = r - m * 96;
    p.xlp[r] = (k < 93) ? p.xl[(size_t)m * 93 + k] : 0.0f;
  }
}

extern "C" void kernel_launch(void* const* d_in, const int* in_sizes, int n_in,
                              void* d_out, int out_size, void* d_ws, size_t ws_size,
                              hipStream_t stream) {
  (void)in_sizes; (void)n_in; (void)out_size;
  static const int dims[5] = {768, 64, 93, 256, 768};
  static const int Kp[5]   = {768, 64, 96, 256, 768};

  const float *adjf[5], *xf[5], *W1f[5], *b1f[5], *W2f[5], *b2f[5];
  for (int v = 0; v < 5; v++) {
    adjf[v] = (const float*)d_in[6 * v + 0];
    xf[v]   = (const float*)d_in[6 * v + 1];
    W1f[v]  = (const float*)d_in[6 * v + 2];
    b1f[v]  = (const float*)d_in[6 * v + 3];
    W2f[v]  = (const float*)d_in[6 * v + 4];
    b2f[v]  = (const float*)d_in[6 * v + 5];
  }

  const size_t VIEW = (size_t)256 * 4096;   // 1,048,576 elements
  const size_t TV   = (size_t)128 * 4096;   // 524,288 elements (T^T per view)
  char* ws = (char*)d_ws;
  size_t off = 0;
  auto carve = [&](size_t bytes) { char* pp = ws + off; off += (bytes + 15) & ~(size_t)15; return pp; };
  u16* W1T[5]; for (int v = 0; v < 5; v++) W1T[v] = (u16*)carve((size_t)256 * Kp[v] * 2);
  u16* W2T[5]; for (int v = 0; v < 5; v++) W2T[v] = (u16*)carve((size_t)128 * 256 * 2);
  float* xlp = (float*)carve((size_t)4096 * 96 * 4);
  u16* Y1T = (u16*)carve(5 * VIEW * 2);      // later reused as TT (T^T, 5MB of 10MB)
  u16* PARTS = (u16*)carve(2 * 5 * VIEW * 2); // bf16 H partials; reused as fp32 final partials
  u16* HT = (u16*)carve(5 * VIEW * 2);       // H row-major [4096][256] per view
  const bool ksplit = ws_size >= off;
  u16* TT = Y1T;            // alias: Y1T dead before TT is written
  float* PARTSF = (float*)PARTS;

  // prep: weight transposes (fp32 -> bf16) + fp32 liwc padding
  PrepParams pp;
  int prepTot = 0;
  for (int v = 0; v < 5; v++) {
    pp.W1[v] = W1f[v]; pp.W1T[v] = W1T[v];
    pp.W2[v] = W2f[v]; pp.W2T[v] = W2T[v];
    pp.d[v] = dims[v]; pp.Kp[v] = Kp[v];
    prepTot += 256 * Kp[v];
  }
  pp.xl = xf[2]; pp.xlp = xlp;
  prepTot += 5 * 128 * 256 + 4096 * 96;
  prep_kernel<<<(prepTot + 255) / 256, 256, 0, stream>>>(pp, prepTot);

  // Phase A: Y1T = (x @ W1)^T   (A fp32, transposed bf16 store)
  Params5 pa;
  for (int v = 0; v < 5; v++)
    pa.v[v] = ViewParams{ (v == 2 ? (const void*)xlp : (const void*)xf[v]), W1T[v], Y1T + v * VIEW,
                          nullptr, Kp[v], Kp[v], 256, Kp[v], 0 };
  gemm_kernel<1, true, false><<<320, 256, 0, stream>>>(pa, 64, 2, 1);

  if (ksplit) {
    // Phase B: PARTS[kc][v] = adj @ Y1 partials, ROW-MAJOR [4096][256], K split in 2.
    // A = adj fp32 directly (no cvt pre-pass; in-register RNE f32->bf16 during
    // fragment load — identical numerics to the old cvt path).
    Params5 pb;
    for (int v = 0; v < 5; v++)
      pb.v[v] = ViewParams{ adjf[v], Y1T + v * VIEW, PARTS + v * VIEW,
                            nullptr, 4096, 4096, 256, 2048, 5 * VIEW };
    gemm_kernel<0, true, false><<<640, 256, 0, stream>>>(pb, 128, 2, 2);

    // combine1: H = relu(sum parts + b1)  (row-major, column bias)
    CombParams c1{ PARTS, HT, { b1f[0], b1f[1], b1f[2], b1f[3], b1f[4] }, 2 };
    comb_h_kernel<<<2560, 256, 0, stream>>>(c1);

    // Phase C': TT = (H @ W2)^T  — tiny GEMM, matches reference associativity
    Params5 pc;
    for (int v = 0; v < 5; v++)
      pc.v[v] = ViewParams{ HT + v * VIEW, W2T[v], TT + v * TV,
                            nullptr, 256, 256, 128, 256, 0 };
    gemm_kernel<1, false, false><<<160, 256, 0, stream>>>(pc, 32, 1, 1);

    // Phase D': PARTSF[kc][v] = adj @ T partials (fp32, row-major [4096][128]),
    // K split in 2, A = adj fp32 directly.
    Params5 pd;
    for (int v = 0; v < 5; v++)
      pd.v[v] = ViewParams{ adjf[v], TT + v * TV, PARTSF + v * TV,
                            nullptr, 4096, 4096, 128, 2048, 5 * TV };
    gemm_kernel<0, true, true><<<320, 256, 0, stream>>>(pd, 64, 1, 2);

    // combine2: out = sum parts + b2
    CombFParams c2{ PARTSF, (float*)d_out, { b2f[0], b2f[1], b2f[2], b2f[3], b2f[4] }, 2 };
    combf_kernel<<<1280, 256, 0, stream>>>(c2);
  } else {
    // fallback: no K-split, fp32 adj reads, direct writes
    Params5 pb;
    for (int v = 0; v < 5; v++)
      pb.v[v] = ViewParams{ adjf[v], Y1T + v * VIEW, HT + v * VIEW,
                            b1f[v], 4096, 4096, 256, 4096, 0 };
    gemm_kernel<6, true, false><<<320, 256, 0, stream>>>(pb, 64, 2, 1);

    Params5 pc;
    for (int v = 0; v < 5; v++)
      pc.v[v] = ViewParams{ HT + v * VIEW, W2T[v], TT + v * TV,
                            nullptr, 256, 256, 128, 256, 0 };
    gemm_kernel<1, false, false><<<160, 256, 0, stream>>>(pc, 32, 1, 1);

    Params5 pd;
    float* outp = (float*)d_out;
    for (int v = 0; v < 5; v++)
      pd.v[v] = ViewParams{ adjf[v], TT + v * TV, outp + v * TV,
                            b2f[v], 4096, 4096, 128, 4096, 0 };
    gemm_kernel<2, true, true><<<160, 256, 0, stream>>>(pd, 32, 1, 1);
  }
}

// Round 6
// 564.134 us; speedup vs baseline: 1.0849x; 1.0179x over previous
//
#include <hip/hip_runtime.h>
#include <stdint.h>

typedef unsigned short u16;
typedef __attribute__((ext_vector_type(8))) __bf16 bf16x8;
typedef __attribute__((ext_vector_type(4))) float f32x4;
typedef __attribute__((ext_vector_type(4))) u16 u16x4;
typedef __attribute__((ext_vector_type(8))) u16 u16x8;

#define BM 128
#define BN 128
#define BK 32
#define MTOT 4096

__device__ __forceinline__ u16 f2bf(float f) {
  union { float f; uint32_t u; } x; x.f = f;
  uint32_t r = x.u + 0x7FFFu + ((x.u >> 16) & 1u);
  return (u16)(r >> 16);
}
__device__ __forceinline__ float bf2f(u16 h) {
  union { uint32_t u; float f; } x; x.u = ((uint32_t)h) << 16;
  return x.f;
}

__device__ __forceinline__ void gload16(const void* g, void* lds) {
  __builtin_amdgcn_global_load_lds(
      (const __attribute__((address_space(1))) void*)g,
      (__attribute__((address_space(3))) void*)lds, 16, 0, 0);
}

template <int N>
__device__ __forceinline__ void wait_vmcnt() {
  asm volatile("s_waitcnt vmcnt(%0)" ::"n"(N) : "memory");
}

struct ViewParams {
  const void* A;    // [M][lda] row-major; fp32 if AF32 else bf16
  const u16* BT;    // [N][ldab] row-major bf16 (B transposed)
  void* C;          // bf16 unless CF32
  const float* bias;
  int ldab, lda, N;
  int kspan;            // K elements per k-chunk (loop length)
  size_t partStride;    // element stride between k-chunk output buffers
};
struct Params5 { ViewParams v[5]; };

// FLAGS: 1 = transposed bf16 store (C is [N][4096]), 2 = +bias, 4 = relu
// Main loop: 3-buffer ring with COUNTED vmcnt (T4 discipline, never 0 mid-loop).
// Per iteration: wait_vmcnt(2*LPS)  [my tile-s loads landed]  -> s_barrier
// [everyone's landed] -> compute(s) -> fence+s_barrier [all done reading] ->
// stage tile s+3 into the just-freed buffer. Loads stay ~3 compute phases in
// flight (~1000+ cyc), covering the ~900-cyc cold-HBM latency that the old
// __syncthreads() vmcnt(0)-drain serialized every step.
template <int FLAGS, bool AF32, bool CF32>
__global__ __launch_bounds__(256) void gemm_kernel(Params5 p, int tilesPerView,
                                                   int ntiles, int kchunks) {
  constexpr int ABYTES = AF32 ? (BM * BK * 4) : (BM * BK * 2);
  constexpr int BUFB = ABYTES + BN * BK * 2;
  constexpr int LPS = AF32 ? 6 : 4;   // gload16 per thread per stage
  __shared__ __align__(16) char smem[3 * BUFB];

  const int bid = blockIdx.x;
  const int view = bid / tilesPerView;
  const int t = bid - view * tilesPerView;
  const int kc = t % kchunks;
  const int t2 = t / kchunks;
  const int nt = t2 % ntiles;
  const int mt = t2 / ntiles;
  ViewParams vp = p.v[view];
  const int ldab = vp.ldab, lda = vp.lda, N = vp.N;
  const int m0 = mt * BM, n0 = nt * BN;
  const int kbase = kc * vp.kspan;

  const int tid = threadIdx.x;
  const int wave = tid >> 6;
  const int lane = tid & 63;

  // ---- B staging (bf16): rows of 32 u16 = 64B = 4 chunks, XOR-4 swizzle
  const int srow = lane >> 2;
  const int slot4 = lane & 3;
  const int rB0 = wave * 32 + srow;
  const int rB1 = rB0 + 16;
  const int cB0 = slot4 ^ ((rB0 >> 1) & 3);
  const int cB1 = slot4 ^ ((rB1 >> 1) & 3);
  const u16* gB0 = vp.BT + (size_t)(n0 + rB0) * ldab + kbase + cB0 * 8;
  const u16* gB1 = vp.BT + (size_t)(n0 + rB1) * ldab + kbase + cB1 * 8;
  const int lB0_off = ABYTES + (wave * 32) * 32 * 2;
  const int lB1_off = ABYTES + (wave * 32 + 16) * 32 * 2;

  // ---- A staging
  const float* gAf[4];
  const u16 *gAb0 = nullptr, *gAb1 = nullptr;
  int lA_off[4];
  if constexpr (AF32) {
    const float* Af = (const float*)vp.A;
    const int arow = lane >> 3;
    const int slot8 = lane & 7;
#pragma unroll
    for (int i = 0; i < 4; i++) {
      int r = wave * 32 + i * 8 + arow;
      int c = slot8 ^ (r & 7);
      gAf[i] = Af + (size_t)(m0 + r) * lda + kbase + c * 4;
      lA_off[i] = (wave * 32 + i * 8) * 32 * 4;
    }
  } else {
    const u16* Ab = (const u16*)vp.A;
    const int rA0 = wave * 32 + srow;
    const int rA1 = rA0 + 16;
    const int cA0 = slot4 ^ ((rA0 >> 1) & 3);
    const int cA1 = slot4 ^ ((rA1 >> 1) & 3);
    gAb0 = Ab + (size_t)(m0 + rA0) * lda + kbase + cA0 * 8;
    gAb1 = Ab + (size_t)(m0 + rA1) * lda + kbase + cA1 * 8;
    lA_off[0] = (wave * 32) * 32 * 2;
    lA_off[1] = (wave * 32 + 16) * 32 * 2;
  }

  // ---- fragment offsets (swizzle-aware); wave covers a 64x64 quadrant
  const int lm = lane & 15;
  const int q = lane >> 4;
  const int wm = (wave >> 1) * 64;
  const int wn = (wave & 1) * 64;
  int aoff0[4], aoff1[4], boff[4];
#pragma unroll
  for (int i = 0; i < 4; i++) {
    int ml = wm + i * 16 + lm;
    if constexpr (AF32) {
      aoff0[i] = ml * 32 + ((2 * q) ^ (ml & 7)) * 4;
      aoff1[i] = ml * 32 + ((2 * q + 1) ^ (ml & 7)) * 4;
    } else {
      aoff0[i] = ml * 32 + (q ^ ((ml >> 1) & 3)) * 8;
    }
    int nl = wn + i * 16 + lm;
    boff[i] = nl * 32 + (q ^ ((nl >> 1) & 3)) * 8;
  }

  f32x4 acc[4][4];
#pragma unroll
  for (int i = 0; i < 4; i++)
#pragma unroll
    for (int j = 0; j < 4; j++) acc[i][j] = 0.0f;

  auto stage = [&](char* bufp) {
    if constexpr (AF32) {
#pragma unroll
      for (int i = 0; i < 4; i++) { gload16(gAf[i], bufp + lA_off[i]); gAf[i] += BK; }
    } else {
      gload16(gAb0, bufp + lA_off[0]);
      gload16(gAb1, bufp + lA_off[1]);
      gAb0 += BK; gAb1 += BK;
    }
    gload16(gB0, bufp + lB0_off);
    gload16(gB1, bufp + lB1_off);
    gB0 += BK; gB1 += BK;
  };

  auto compute = [&](const char* bufp) {
    bf16x8 af[4], bfr[4];
#pragma unroll
    for (int i = 0; i < 4; i++) {
      if constexpr (AF32) {
        f32x4 lo = *(const f32x4*)((const float*)bufp + aoff0[i]);
        f32x4 hi = *(const f32x4*)((const float*)bufp + aoff1[i]);
        bf16x8 a;
#pragma unroll
        for (int tt = 0; tt < 4; tt++) { a[tt] = (__bf16)lo[tt]; a[tt + 4] = (__bf16)hi[tt]; }
        af[i] = a;
      } else {
        af[i] = *(const bf16x8*)((const u16*)bufp + aoff0[i]);
      }
    }
    const u16* Bs = (const u16*)(bufp + ABYTES);
#pragma unroll
    for (int j = 0; j < 4; j++) bfr[j] = *(const bf16x8*)(Bs + boff[j]);
#pragma unroll
    for (int i = 0; i < 4; i++)
#pragma unroll
      for (int j = 0; j < 4; j++)
        acc[i][j] = __builtin_amdgcn_mfma_f32_16x16x32_bf16(af[i], bfr[j], acc[i][j], 0, 0, 0);
  };

  const int nsteps = vp.kspan / BK;
  char* b0 = smem;
  char* b1 = smem + BUFB;
  char* b2 = smem + 2 * BUFB;
  // prologue: stage up to 3 tiles ahead
  stage(b0);
  if (nsteps > 1) stage(b1);
  if (nsteps > 2) stage(b2);

  for (int s = 0; s < nsteps; s++) {
    const int rem = nsteps - 1 - s;   // tiles after this one
    // outstanding tiles allowed = min(2, rem); wait for MY tile-s loads,
    // THEN barrier => everyone's tile-s loads landed (race-free discipline).
    if (rem >= 2)      wait_vmcnt<2 * LPS>();
    else if (rem == 1) wait_vmcnt<LPS>();
    else               wait_vmcnt<0>();
    __builtin_amdgcn_s_barrier();
    compute(b0);
    if (rem >= 3) {
      asm volatile("" ::: "memory");     // keep LDS reads above the barrier
      __builtin_amdgcn_s_barrier();      // all waves done reading b0
      stage(b0);                         // stage tile s+3 into freed buffer
    }
    char* tmp = b0; b0 = b1; b1 = b2; b2 = tmp;
  }

  // ---- epilogue. C/D layout: col = lane&15, row = quad*4 + reg.
#pragma unroll
  for (int j = 0; j < 4; j++) {
    const int n = n0 + wn + j * 16 + lm;
    float bv = 0.0f;
    if (FLAGS & 2) bv = vp.bias[n];
#pragma unroll
    for (int i = 0; i < 4; i++) {
      const int mb = m0 + wm + i * 16 + q * 4;
      float v0 = acc[i][j][0], v1 = acc[i][j][1], v2 = acc[i][j][2], v3 = acc[i][j][3];
      if (FLAGS & 2) { v0 += bv; v1 += bv; v2 += bv; v3 += bv; }
      if (FLAGS & 4) {
        v0 = fmaxf(v0, 0.0f); v1 = fmaxf(v1, 0.0f);
        v2 = fmaxf(v2, 0.0f); v3 = fmaxf(v3, 0.0f);
      }
      if constexpr ((FLAGS & 1) != 0) {
        u16x4 pk;
        pk[0] = f2bf(v0); pk[1] = f2bf(v1); pk[2] = f2bf(v2); pk[3] = f2bf(v3);
        *(u16x4*)((u16*)vp.C + (size_t)kc * vp.partStride + (size_t)n * MTOT + mb) = pk;
      } else if constexpr (CF32) {
        float* cp = (float*)vp.C + (size_t)kc * vp.partStride + (size_t)mb * N + n;
        cp[0] = v0; cp[N] = v1; cp[2 * N] = v2; cp[3 * N] = v3;
      } else {
        u16* cp = (u16*)vp.C + (size_t)kc * vp.partStride + (size_t)mb * N + n;
        cp[0] = f2bf(v0); cp[N] = f2bf(v1); cp[2 * N] = f2bf(v2); cp[3 * N] = f2bf(v3);
      }
    }
  }
}

// combine k-chunk bf16 partials of H (row-major [4096][256] per view):
// H = relu(sum_kc parts + b1), bias indexed by COLUMN (e & 255).
struct CombParams { const u16* parts; u16* out; const float* b[5]; int kchunks; };
__global__ __launch_bounds__(256) void comb_h_kernel(CombParams cp) {
  int idx = blockIdx.x * 256 + threadIdx.x;   // 5 * 2^17 threads exactly
  int v = idx >> 17;
  int e = (idx & 131071) << 3;
  float acc[8] = {0, 0, 0, 0, 0, 0, 0, 0};
  for (int kc = 0; kc < cp.kchunks; kc++) {
    u16x8 t = *(const u16x8*)(cp.parts + (((size_t)(kc * 5 + v)) << 20) + e);
#pragma unroll
    for (int j = 0; j < 8; j++) acc[j] += bf2f(t[j]);
  }
  const float* bp = cp.b[v] + (e & 255);
  u16x8 o;
#pragma unroll
  for (int j = 0; j < 8; j++) o[j] = f2bf(fmaxf(acc[j] + bp[j], 0.0f));
  *(u16x8*)(cp.out + (((size_t)v) << 20) + e) = o;
}

// combine fp32 final partials: out = sum_kc parts + b2 (row-major [4096][128])
struct CombFParams { const float* parts; float* out; const float* b[5]; int kchunks; };
__global__ __launch_bounds__(256) void combf_kernel(CombFParams cp) {
  int idx = blockIdx.x * 256 + threadIdx.x;   // 5 * 2^16 threads exactly
  int v = idx >> 16;
  int e = (idx & 65535) << 3;
  float acc[8] = {0, 0, 0, 0, 0, 0, 0, 0};
  for (int kc = 0; kc < cp.kchunks; kc++) {
    const float* pp = cp.parts + (((size_t)(kc * 5 + v)) << 19) + e;
    f32x4 a = *(const f32x4*)pp;
    f32x4 b = *(const f32x4*)(pp + 4);
#pragma unroll
    for (int j = 0; j < 4; j++) { acc[j] += a[j]; acc[j + 4] += b[j]; }
  }
  const float* bp = cp.b[v] + (e & 127);
  f32x4 o0, o1;
#pragma unroll
  for (int j = 0; j < 4; j++) { o0[j] = acc[j] + bp[j]; o1[j] = acc[j + 4] + bp[j + 4]; }
  float* op = cp.out + (((size_t)v) << 19) + e;
  *(f32x4*)op = o0;
  *(f32x4*)(op + 4) = o1;
}

struct PrepParams {
  const float* W1[5]; u16* W1T[5];
  const float* W2[5]; u16* W2T[5];
  const float* xl; float* xlp;
  int d[5]; int Kp[5];
};

__global__ void prep_kernel(PrepParams p, int total) {
  int idx = blockIdx.x * 256 + threadIdx.x;
  if (idx >= total) return;
  int off = 0;
#pragma unroll
  for (int v = 0; v < 5; v++) {
    int sz = 256 * p.Kp[v];
    if (idx < off + sz) {
      int r = idx - off;
      int n = r / p.Kp[v];
      int k = r - n * p.Kp[v];
      p.W1T[v][r] = (k < p.d[v]) ? f2bf(p.W1[v][(size_t)k * 256 + n]) : (u16)0;
      return;
    }
    off += sz;
  }
#pragma unroll
  for (int v = 0; v < 5; v++) {
    if (idx < off + 128 * 256) {
      int r = idx - off;
      int n = r >> 8, k = r & 255;
      p.W2T[v][r] = f2bf(p.W2[v][(size_t)k * 128 + n]);
      return;
    }
    off += 128 * 256;
  }
  {
    int r = idx - off;
    int m = r / 96, k = r - m * 96;
    p.xlp[r] = (k < 93) ? p.xl[(size_t)m * 93 + k] : 0.0f;
  }
}

extern "C" void kernel_launch(void* const* d_in, const int* in_sizes, int n_in,
                              void* d_out, int out_size, void* d_ws, size_t ws_size,
                              hipStream_t stream) {
  (void)in_sizes; (void)n_in; (void)out_size;
  static const int dims[5] = {768, 64, 93, 256, 768};
  static const int Kp[5]   = {768, 64, 96, 256, 768};

  const float *adjf[5], *xf[5], *W1f[5], *b1f[5], *W2f[5], *b2f[5];
  for (int v = 0; v < 5; v++) {
    adjf[v] = (const float*)d_in[6 * v + 0];
    xf[v]   = (const float*)d_in[6 * v + 1];
    W1f[v]  = (const float*)d_in[6 * v + 2];
    b1f[v]  = (const float*)d_in[6 * v + 3];
    W2f[v]  = (const float*)d_in[6 * v + 4];
    b2f[v]  = (const float*)d_in[6 * v + 5];
  }

  const size_t VIEW = (size_t)256 * 4096;   // 1,048,576 elements
  const size_t TV   = (size_t)128 * 4096;   // 524,288 elements (T^T per view)
  char* ws = (char*)d_ws;
  size_t off = 0;
  auto carve = [&](size_t bytes) { char* pp = ws + off; off += (bytes + 15) & ~(size_t)15; return pp; };
  u16* W1T[5]; for (int v = 0; v < 5; v++) W1T[v] = (u16*)carve((size_t)256 * Kp[v] * 2);
  u16* W2T[5]; for (int v = 0; v < 5; v++) W2T[v] = (u16*)carve((size_t)128 * 256 * 2);
  float* xlp = (float*)carve((size_t)4096 * 96 * 4);
  u16* Y1T = (u16*)carve(5 * VIEW * 2);       // later reused as TT (T^T, 5MB of 10MB)
  u16* PARTS = (u16*)carve((size_t)4 * 5 * TV * 4); // 40MB: B bf16 partials (20MB) / D fp32 partials x4
  u16* HT = (u16*)carve(5 * VIEW * 2);        // H row-major [4096][256] per view
  const bool ksplit = ws_size >= off;
  u16* TT = Y1T;            // alias: Y1T dead before TT is written
  float* PARTSF = (float*)PARTS;

  // prep: weight transposes (fp32 -> bf16) + fp32 liwc padding
  PrepParams pp;
  int prepTot = 0;
  for (int v = 0; v < 5; v++) {
    pp.W1[v] = W1f[v]; pp.W1T[v] = W1T[v];
    pp.W2[v] = W2f[v]; pp.W2T[v] = W2T[v];
    pp.d[v] = dims[v]; pp.Kp[v] = Kp[v];
    prepTot += 256 * Kp[v];
  }
  pp.xl = xf[2]; pp.xlp = xlp;
  prepTot += 5 * 128 * 256 + 4096 * 96;
  prep_kernel<<<(prepTot + 255) / 256, 256, 0, stream>>>(pp, prepTot);

  // Phase A: Y1T = (x @ W1)^T   (A fp32, transposed bf16 store)
  Params5 pa;
  for (int v = 0; v < 5; v++)
    pa.v[v] = ViewParams{ (v == 2 ? (const void*)xlp : (const void*)xf[v]), W1T[v], Y1T + v * VIEW,
                          nullptr, Kp[v], Kp[v], 256, Kp[v], 0 };
  gemm_kernel<1, true, false><<<320, 256, 0, stream>>>(pa, 64, 2, 1);

  if (ksplit) {
    // Phase B: PARTS[kc][v] = adj @ Y1 partials, ROW-MAJOR [4096][256], K split in 2.
    Params5 pb;
    for (int v = 0; v < 5; v++)
      pb.v[v] = ViewParams{ adjf[v], Y1T + v * VIEW, PARTS + v * VIEW,
                            nullptr, 4096, 4096, 256, 2048, 5 * VIEW };
    gemm_kernel<0, true, false><<<640, 256, 0, stream>>>(pb, 128, 2, 2);

    // combine1: H = relu(sum parts + b1)  (row-major, column bias)
    CombParams c1{ PARTS, HT, { b1f[0], b1f[1], b1f[2], b1f[3], b1f[4] }, 2 };
    comb_h_kernel<<<2560, 256, 0, stream>>>(c1);

    // Phase C': TT = (H @ W2)^T  — tiny GEMM, matches reference associativity
    Params5 pc;
    for (int v = 0; v < 5; v++)
      pc.v[v] = ViewParams{ HT + v * VIEW, W2T[v], TT + v * TV,
                            nullptr, 256, 256, 128, 256, 0 };
    gemm_kernel<1, false, false><<<160, 256, 0, stream>>>(pc, 32, 1, 1);

    // Phase D': PARTSF[kc][v] = adj @ T partials (fp32, row-major [4096][128]),
    // K split in 4 (grid 640 => >=2 blocks/CU for latency hiding).
    Params5 pd;
    for (int v = 0; v < 5; v++)
      pd.v[v] = ViewParams{ adjf[v], TT + v * TV, PARTSF + v * TV,
                            nullptr, 4096, 4096, 128, 1024, 5 * TV };
    gemm_kernel<0, true, true><<<640, 256, 0, stream>>>(pd, 128, 1, 4);

    // combine2: out = sum parts + b2
    CombFParams c2{ PARTSF, (float*)d_out, { b2f[0], b2f[1], b2f[2], b2f[3], b2f[4] }, 4 };
    combf_kernel<<<1280, 256, 0, stream>>>(c2);
  } else {
    // fallback: no K-split, fp32 adj reads, direct writes
    Params5 pb;
    for (int v = 0; v < 5; v++)
      pb.v[v] = ViewParams{ adjf[v], Y1T + v * VIEW, HT + v * VIEW,
                            b1f[v], 4096, 4096, 256, 4096, 0 };
    gemm_kernel<6, true, false><<<320, 256, 0, stream>>>(pb, 64, 2, 1);

    Params5 pc;
    for (int v = 0; v < 5; v++)
      pc.v[v] = ViewParams{ HT + v * VIEW, W2T[v], TT + v * TV,
                            nullptr, 256, 256, 128, 256, 0 };
    gemm_kernel<1, false, false><<<160, 256, 0, stream>>>(pc, 32, 1, 1);

    Params5 pd;
    float* outp = (float*)d_out;
    for (int v = 0; v < 5; v++)
      pd.v[v] = ViewParams{ adjf[v], TT + v * TV, outp + v * TV,
                            b2f[v], 4096, 4096, 128, 4096, 0 };
    gemm_kernel<2, true, true><<<160, 256, 0, stream>>>(pd, 32, 1, 1);
  }
}